// Round 7
// baseline (8829.838 us; speedup 1.0000x reference)
//
#include <hip/hip_runtime.h>
#include <hip/hip_bf16.h>
#include <string.h>

// Problem constants
#define T_STEPS 512
#define BATCH   128
#define DIM     256
#define HID     256
#define NLAYERS 4

typedef unsigned int  uint4v  __attribute__((ext_vector_type(4)));
typedef unsigned int  uint2v  __attribute__((ext_vector_type(2)));
typedef short         short8  __attribute__((ext_vector_type(8)));
typedef float         float4v __attribute__((ext_vector_type(4)));

// ws layout (TOTAL 512KB):
//   [0, 512KB) : h exchange ring, 4 slots x (8 clusters x 16 rows x 128 pairs
//                x 8B). pair = [bf16x2 packed h | 32-bit round tag]
//                (tag-in-data sync). R0-proven mechanism, unchanged.
#define SLOT_BYTES  (128 * 1024)
#define NSLOTS      4
#define HBUF_BYTES  (NSLOTS * SLOT_BYTES)

__device__ __forceinline__ short8 as_s8(uint4v u) {
  union { uint4v u; short8 s; } x; x.u = u; return x.s;
}
__device__ __forceinline__ float sigf(float x) {
  return 1.0f / (1.0f + __expf(-x));
}
__device__ __forceinline__ float tanh_fast(float x) {
  x = fminf(fmaxf(x, -15.0f), 15.0f);
  float e = __expf(2.0f * x);
  return (e - 1.0f) / (e + 1.0f);
}
// round-to-nearest-even f32 -> bf16 (inputs always finite here)
__device__ __forceinline__ unsigned short f2bf(float a) {
  unsigned ua = __builtin_bit_cast(unsigned, a);
  return (unsigned short)((ua + 0x7FFFu + ((ua >> 16) & 1u)) >> 16);
}
__device__ __forceinline__ unsigned pack_bf16x2(float a, float b) {
  return (unsigned)f2bf(a) | ((unsigned)f2bf(b) << 16);
}
__device__ __forceinline__ uint4v extract_frag(uint4v a, uint4v b) {
  uint4v f; f.x = a.x; f.y = a.z; f.z = b.x; f.w = b.z; return f;
}
__device__ __forceinline__ unsigned tagbad(uint4v a, uint4v b, unsigned tag) {
  return (a.y ^ tag) | (a.w ^ tag) | (b.y ^ tag) | (b.w ^ tag);
}

// LDS flag ops (workgroup scope). R6-bug lesson: flag RMW/stores must be
// ONE-PER-WAVE (lane 0). The release's lgkmcnt(0) drains the WHOLE WAVE's
// prior LDS writes (lgkmcnt is a per-wave counter), so lane-0-only release
// still orders all 64 lanes' tile/hsh stores. Per-lane addrel was the R6
// race: tcnt jumped 64x per helper, v0 read tiles before they were written.
__device__ __forceinline__ unsigned ldacq(unsigned* p) {
  return __hip_atomic_load(p, __ATOMIC_ACQUIRE, __HIP_MEMORY_SCOPE_WORKGROUP);
}
__device__ __forceinline__ void strel(unsigned* p, unsigned val) {
  __hip_atomic_store(p, val, __ATOMIC_RELEASE, __HIP_MEMORY_SCOPE_WORKGROUP);
}
__device__ __forceinline__ void addrel(unsigned* p) {
  __hip_atomic_fetch_add(p, 1u, __ATOMIC_RELEASE, __HIP_MEMORY_SCOPE_WORKGROUP);
}
__device__ __forceinline__ void waitflag(unsigned* p, unsigned tgt) {
  int it = 0;
  while (ldacq(p) < tgt) {
    if (++it > 512) __builtin_amdgcn_s_sleep(1);
  }
}

// 16 device-scope (sc0 sc1) 16B loads covering this lane's 8 A-fragments
// worth of [data|tag] pairs; single waitcnt INSIDE the asm — this is what
// makes the output registers safe to consume/reallocate after the macro
// (R4 lesson: counted-vmcnt exits leave in-flight writes that clobber
// compiler-reallocated VGPRs).
#define GLD16(A0,B0,A1,B1,A2,B2,A3,B3,A4,B4,A5,B5,A6,B6,A7,B7, ADDR)       \
  asm volatile(                                                             \
      "global_load_dwordx4 %0, %16, off offset:0 sc0 sc1\n\t"               \
      "global_load_dwordx4 %1, %16, off offset:16 sc0 sc1\n\t"              \
      "global_load_dwordx4 %2, %16, off offset:128 sc0 sc1\n\t"             \
      "global_load_dwordx4 %3, %16, off offset:144 sc0 sc1\n\t"             \
      "global_load_dwordx4 %4, %16, off offset:256 sc0 sc1\n\t"             \
      "global_load_dwordx4 %5, %16, off offset:272 sc0 sc1\n\t"             \
      "global_load_dwordx4 %6, %16, off offset:384 sc0 sc1\n\t"             \
      "global_load_dwordx4 %7, %16, off offset:400 sc0 sc1\n\t"             \
      "global_load_dwordx4 %8, %16, off offset:512 sc0 sc1\n\t"             \
      "global_load_dwordx4 %9, %16, off offset:528 sc0 sc1\n\t"             \
      "global_load_dwordx4 %10, %16, off offset:640 sc0 sc1\n\t"            \
      "global_load_dwordx4 %11, %16, off offset:656 sc0 sc1\n\t"            \
      "global_load_dwordx4 %12, %16, off offset:768 sc0 sc1\n\t"            \
      "global_load_dwordx4 %13, %16, off offset:784 sc0 sc1\n\t"            \
      "global_load_dwordx4 %14, %16, off offset:896 sc0 sc1\n\t"            \
      "global_load_dwordx4 %15, %16, off offset:912 sc0 sc1\n\t"            \
      "s_waitcnt vmcnt(0)"                                                  \
      : "=&v"(A0), "=&v"(B0), "=&v"(A1), "=&v"(B1),                         \
        "=&v"(A2), "=&v"(B2), "=&v"(A3), "=&v"(B3),                         \
        "=&v"(A4), "=&v"(B4), "=&v"(A5), "=&v"(B5),                         \
        "=&v"(A6), "=&v"(B6), "=&v"(A7), "=&v"(B7)                          \
      : "v"(ADDR)                                                           \
      : "memory")

// Poll until every consumed pair carries tag==TAG, then unpack 8 A-frags.
// Hot spin for 16 iters, then s_sleep(1) backoff. Stale reads only show OLD
// tags (monotonic) — never false-positive.
#define POLL8T(F0,F1,F2,F3,F4,F5,F6,F7, ADDR, TAG)                          \
  {                                                                         \
    uint4v _a0,_b0,_a1,_b1,_a2,_b2,_a3,_b3,_a4,_b4,_a5,_b5,_a6,_b6,_a7,_b7; \
    for (int _it = 0;; ++_it) {                                             \
      GLD16(_a0,_b0,_a1,_b1,_a2,_b2,_a3,_b3,_a4,_b4,_a5,_b5,_a6,_b6,_a7,_b7,\
            ADDR);                                                          \
      unsigned _bad = tagbad(_a0,_b0,TAG) | tagbad(_a1,_b1,TAG) |           \
                      tagbad(_a2,_b2,TAG) | tagbad(_a3,_b3,TAG) |           \
                      tagbad(_a4,_b4,TAG) | tagbad(_a5,_b5,TAG) |           \
                      tagbad(_a6,_b6,TAG) | tagbad(_a7,_b7,TAG);            \
      if (__all((int)(_bad == 0u)) || _it > (1 << 16)) break;               \
      if (_it >= 16) __builtin_amdgcn_s_sleep(1);                           \
    }                                                                       \
    F0 = extract_frag(_a0,_b0); F1 = extract_frag(_a1,_b1);                 \
    F2 = extract_frag(_a2,_b2); F3 = extract_frag(_a3,_b3);                 \
    F4 = extract_frag(_a4,_b4); F5 = extract_frag(_a5,_b5);                 \
    F6 = extract_frag(_a6,_b6); F7 = extract_frag(_a7,_b7);                 \
  }

// Publish: proven R0 form (sc0 sc1; R3 showed nt regresses).
#define PUBLISH(ADDR, PACKED, TAG)                                          \
  {                                                                         \
    uint2v _pv; _pv.x = (PACKED); _pv.y = (TAG);                            \
    asm volatile("global_store_dwordx2 %0, %1, off sc0 sc1"                 \
                 :: "v"(ADDR), "v"(_pv) : "memory");                        \
  }

#define MFMA1(ACC, HF, BF)                                                  \
  ACC = __builtin_amdgcn_mfma_f32_16x16x32_bf16(as_s8(HF), BF, ACC, 0, 0, 0)

// ---------------------------------------------------------------------------
// R7 = R6 barrier-free orchestration + the lane-0 flag fix (R6's race) +
// publish-before-out at i==3. 8 clusters x 16 wgs x 4 waves. Cross-wg ring
// identical to R0/R5. Intra-wg:
//  * per-gate wave ownership: v1={Wr,Tr}, v2={Wz,Tz}, v3={Wl,Tn}; v0=
//    {Ch,Cx,Wt} + f32 h-state in MFMA ACC LAYOUT (col=lane&15,
//    row=(lane>>4)*4+j — same mapping as R5's proven tiles indexing).
//  * __syncthreads replaced by 2 monotonic LDS flags (acquire/release,
//    lane-0-only stores/adds): v0: poll -> hsh -> hsflag=r+1; helpers: wait
//    hsflag -> 8 MFMAs (+sigmoid) -> tile -> lane0 tcnt++; v0: wait tcnt ->
//    lane-local combine -> publish (4 pair-stores from even-col lanes).
//  * v0's Cx/Wt x-MFMAs run pre-poll (delay-aligns first poll sample);
//    helpers' x-MFMAs overlap v0's poll.
//  * v1 keeps the x-prefetch (issue i==0, pack->xsh i==1); xsh/hsh/tiles
//    WAR hazards ordered by the release->acquire chains (audited r6/r7).
// ---------------------------------------------------------------------------
__launch_bounds__(256, 1)
__global__ void rnn_main(const float* __restrict__ x,
                         const int* __restrict__ lengths,
                         const float* __restrict__ Wr,
                         const float* __restrict__ Wz,
                         const float* __restrict__ Wl,
                         const float* __restrict__ Wt,
                         const float* __restrict__ Cx,
                         const float* __restrict__ Ch,
                         const float* __restrict__ Tr,
                         const float* __restrict__ Tz,
                         const float* __restrict__ Tn,
                         unsigned char* __restrict__ hbuf,
                         float* __restrict__ out) {
  const int tid  = threadIdx.x;
  const int lane = tid & 63;
  const int v    = tid >> 6;
  const int bid  = blockIdx.x;
  const int c    = bid & 7;    // cluster (batch slice)
  const int w    = bid >> 3;   // column-chunk owner within cluster

  __shared__ float    tiles[3][256];   // [gate][lane*4+j], acc layout
  __shared__ uint4v   hsh[8][64];      // polled A-frag broadcast (8 KB)
  __shared__ uint4v   xsh[8][64];      // prefetched packed x frags (8 KB)
  __shared__ unsigned hsflag;          // v0 -> helpers: hsh ready (round+1)
  __shared__ unsigned tcnt;            // helpers -> v0: tiles produced

  // ---- load + convert persistent weight B-fragments (one-time gather) ----
  // Fragment layout: lane l holds B[k = kt*32 + (l>>4)*8 + j][col0 + (l&15)].
  // Matrix ids: 0..2 = W{r,z,l}[256:512] (h-part), 3 = Ch, 4..6 = W{r,z,l}
  // [0:256] (x-part), 7 = Cx, 8 = Wt, 9..12 = Tr_i, 13..16 = Tz_i,
  // 17..20 = Tn_i.  SCHED: v0 = combiner {Ch,Cx,Wt}; helpers own gates.
  short8 Wf[6][8];
  {
    const int SCHED[4][6] = {{3, 7, 8, 3, 3, 3},
                             {0, 4, 9, 10, 11, 12},
                             {1, 5, 13, 14, 15, 16},
                             {2, 6, 17, 18, 19, 20}};
    const int colg = w * 16 + (lane & 15);
#pragma unroll
    for (int s = 0; s < 6; ++s) {
      const int m = SCHED[v][s];
      const float* base;
      int ro = 0;
      if      (m == 0)  { base = Wr; ro = 256; }
      else if (m == 1)  { base = Wz; ro = 256; }
      else if (m == 2)  { base = Wl; ro = 256; }
      else if (m == 3)  { base = Ch; }
      else if (m == 4)  { base = Wr; }
      else if (m == 5)  { base = Wz; }
      else if (m == 6)  { base = Wl; }
      else if (m == 7)  { base = Cx; }
      else if (m == 8)  { base = Wt; }
      else if (m <= 12) { base = Tr + (size_t)(m - 9)  * HID * HID; }
      else if (m <= 16) { base = Tz + (size_t)(m - 13) * HID * HID; }
      else              { base = Tn + (size_t)(m - 17) * HID * HID; }
#pragma unroll
      for (int kt = 0; kt < 8; ++kt) {
        const int k0 = ro + kt * 32 + (lane >> 4) * 8;
        short8 f;
#pragma unroll
        for (int j = 0; j < 8; ++j)
          f[j] = (short)f2bf(base[(size_t)(k0 + j) * HID + colg]);
        Wf[s][kt] = f;
      }
    }
  }

  if (tid == 0) { hsflag = 0u; tcnt = 0u; }

  const int rb  = (lane >> 4) * 4;   // acc-layout row base for this lane
  const int col = lane & 15;         // acc-layout column

  int   len4[4];
  float h_state[4], hfroz[4];
  if (v == 0) {
#pragma unroll
    for (int j = 0; j < 4; ++j) {
      len4[j]    = lengths[c * 16 + rb + j];
      h_state[j] = 0.0f;
      hfroz[j]   = 0.0f;
    }
  }

  const float* xbase =
      x + ((size_t)c * 16 + (lane & 15)) * DIM + (lane >> 4) * 8;

  // Prologue: v1 stages packed x for t=0 into xsh (blocking; once).
  if (v == 1) {
#pragma unroll
    for (int kt = 0; kt < 8; ++kt) {
      float4v xa = *(const float4v*)(xbase + kt * 32);
      float4v xb = *(const float4v*)(xbase + kt * 32 + 4);
      uint4v f;
      f.x = pack_bf16x2(xa.x, xa.y);
      f.y = pack_bf16x2(xa.z, xa.w);
      f.z = pack_bf16x2(xb.x, xb.y);
      f.w = pack_bf16x2(xb.z, xb.w);
      xsh[kt][lane] = f;
    }
  }
  __syncthreads();   // the ONLY barrier

  // lane byte offset into an h slot for A-frag [data|tag] pair loads.
  const unsigned vh = (unsigned)((c * 16 + (lane & 15)) * 1024 + (lane >> 4) * 32);
  // v0 publish base (even-col lanes): rows rb..rb+3 at colpair col>>1;
  // per-row stride = 128 pairs * 8B = 1024B. Same addresses/bytes as R5.
  const unsigned pub0 =
      (unsigned)(((c * 16 + rb) * 128 + w * 8 + (col >> 1)) * 8);

  unsigned exp_cnt = 0;

  for (int t = 0; t < T_STEPS; ++t) {
    const int r0 = t * 5;
    float4v xra[8], xrb8[8];   // v1's raw next-step x (live i==0 -> i==1)
    // ======================= round A (cell gates) =======================
    {
      uint4v xf[8];
#pragma unroll
      for (int kt = 0; kt < 8; ++kt) xf[kt] = xsh[kt][lane];

      if (v == 0) {
        // pre-poll: x-only products (Cx, Wt) — off the h critical path;
        // also delay-aligns the first poll sample past publish visibility.
        float4v acx = {0.f,0.f,0.f,0.f}, awt = {0.f,0.f,0.f,0.f};
#pragma unroll
        for (int kt = 0; kt < 8; ++kt) {
          MFMA1(acx, xf[kt], Wf[1][kt]);
          MFMA1(awt, xf[kt], Wf[2][kt]);
        }
        uint4v hf[8];
        const unsigned char* ap =
            hbuf + (size_t)((r0 - 1) & 3) * SLOT_BYTES + vh;
        POLL8T(hf[0],hf[1],hf[2],hf[3],hf[4],hf[5],hf[6],hf[7],
               ap, (unsigned)r0);
#pragma unroll
        for (int k = 0; k < 8; ++k) hsh[k][lane] = hf[k];
        if (lane == 0) strel(&hsflag, (unsigned)(r0 + 1));
        float4v c1 = {0.f,0.f,0.f,0.f}, c2 = {0.f,0.f,0.f,0.f};
#pragma unroll
        for (int kt = 0; kt < 8; kt += 2) {
          MFMA1(c1, hf[kt],     Wf[0][kt]);
          MFMA1(c2, hf[kt + 1], Wf[0][kt + 1]);
        }
        float4v ach = c1 + c2;
        exp_cnt += 3;
        waitflag(&tcnt, exp_cnt);
        float hnew[4];
#pragma unroll
        for (int j = 0; j < 4; ++j) {
          float r  = tiles[0][lane * 4 + j];
          float z  = tiles[1][lane * 4 + j];
          float lg = tiles[2][lane * 4 + j];
          float n  = tanh_fast(acx[j] + r * ach[j]) + lg * awt[j];
          hnew[j]  = (1.0f - z) * h_state[j] + z * n;
          h_state[j] = hnew[j];
        }
        float hp0 = __shfl_xor(hnew[0], 1), hp1 = __shfl_xor(hnew[1], 1),
              hp2 = __shfl_xor(hnew[2], 1), hp3 = __shfl_xor(hnew[3], 1);
        if (!(lane & 1)) {
          unsigned char* pp = hbuf + (size_t)(r0 & 3) * SLOT_BYTES + pub0;
          PUBLISH(pp,        pack_bf16x2(hnew[0], hp0), (unsigned)(r0 + 1));
          PUBLISH(pp + 1024, pack_bf16x2(hnew[1], hp1), (unsigned)(r0 + 1));
          PUBLISH(pp + 2048, pack_bf16x2(hnew[2], hp2), (unsigned)(r0 + 1));
          PUBLISH(pp + 3072, pack_bf16x2(hnew[3], hp3), (unsigned)(r0 + 1));
        }
      } else {
        // helper gate g = v-1: x-part overlaps v0's poll, then h-part
        float4v a1 = {0.f,0.f,0.f,0.f}, a2 = {0.f,0.f,0.f,0.f};
#pragma unroll
        for (int kt = 0; kt < 8; kt += 2) {
          MFMA1(a1, xf[kt],     Wf[1][kt]);
          MFMA1(a2, xf[kt + 1], Wf[1][kt + 1]);
        }
        waitflag(&hsflag, (unsigned)(r0 + 1));
        uint4v hf[8];
#pragma unroll
        for (int k = 0; k < 8; ++k) hf[k] = hsh[k][lane];
#pragma unroll
        for (int kt = 0; kt < 8; kt += 2) {
          MFMA1(a1, hf[kt],     Wf[0][kt]);
          MFMA1(a2, hf[kt + 1], Wf[0][kt + 1]);
        }
        float4v a = a1 + a2;
#pragma unroll
        for (int j = 0; j < 4; ++j) a[j] = sigf(a[j]);   // r,z,l: all sigmoid
        *(float4v*)&tiles[v - 1][lane * 4] = a;
        if (lane == 0) addrel(&tcnt);   // R6-bug fix: one add PER WAVE
      }
    }
    // ======================= transition layers =======================
#pragma unroll
    for (int i = 0; i < NLAYERS; ++i) {
      const int ri = r0 + 1 + i;
      if (v == 0) {
        uint4v hf[8];
        const unsigned char* ap =
            hbuf + (size_t)((ri - 1) & 3) * SLOT_BYTES + vh;
        POLL8T(hf[0],hf[1],hf[2],hf[3],hf[4],hf[5],hf[6],hf[7],
               ap, (unsigned)ri);
#pragma unroll
        for (int k = 0; k < 8; ++k) hsh[k][lane] = hf[k];
        if (lane == 0) strel(&hsflag, (unsigned)(ri + 1));
        exp_cnt += 3;
        waitflag(&tcnt, exp_cnt);
        float hnew[4];
        bool  act4[4];
#pragma unroll
        for (int j = 0; j < 4; ++j) {
          float rr = tiles[0][lane * 4 + j];
          float zz = tiles[1][lane * 4 + j];
          float tn = tiles[2][lane * 4 + j];
          float nn = tanh_fast(rr * tn);
          hnew[j]  = (1.0f - zz) * nn + zz * h_state[j];
          act4[j]  = true;
        }
        if (i == NLAYERS - 1) {
#pragma unroll
          for (int j = 0; j < 4; ++j) {
            act4[j] = (t < len4[j]);
            float hv = act4[j] ? hnew[j] : hfroz[j];  // freeze past seq end
            hnew[j]  = hv;
            hfroz[j] = hv;
          }
        }
#pragma unroll
        for (int j = 0; j < 4; ++j) h_state[j] = hnew[j];
        // publish FIRST (critical path for next round's pollers) ...
        float hp0 = __shfl_xor(hnew[0], 1), hp1 = __shfl_xor(hnew[1], 1),
              hp2 = __shfl_xor(hnew[2], 1), hp3 = __shfl_xor(hnew[3], 1);
        if (!(lane & 1)) {
          unsigned char* pp = hbuf + (size_t)(ri & 3) * SLOT_BYTES + pub0;
          PUBLISH(pp,        pack_bf16x2(hnew[0], hp0), (unsigned)(ri + 1));
          PUBLISH(pp + 1024, pack_bf16x2(hnew[1], hp1), (unsigned)(ri + 1));
          PUBLISH(pp + 2048, pack_bf16x2(hnew[2], hp2), (unsigned)(ri + 1));
          PUBLISH(pp + 3072, pack_bf16x2(hnew[3], hp3), (unsigned)(ri + 1));
        }
        // ... then the out-store (off the inter-wg critical path)
        if (i == NLAYERS - 1) {
#pragma unroll
          for (int j = 0; j < 4; ++j) {
            float ov = act4[j] ? hnew[j] : 0.0f;      // out = m ? hn : 0
            out[((size_t)t * BATCH + c * 16 + rb + j) * HID + w * 16 + col] = ov;
          }
        }
      } else {
        // v1 x-prefetch (hidden in helper slack; ordering to xsh readers is
        // via v1's tcnt release -> v0 hsflag release -> reader acquire chain)
        if (v == 1 && t + 1 < T_STEPS) {
          if (i == 0) {
            const float* xq = xbase + (size_t)(t + 1) * BATCH * DIM;
#pragma unroll
            for (int kt = 0; kt < 8; ++kt) {
              xra[kt]  = *(const float4v*)(xq + kt * 32);
              xrb8[kt] = *(const float4v*)(xq + kt * 32 + 4);
            }
          }
          if (i == 1) {
#pragma unroll
            for (int kt = 0; kt < 8; ++kt) {
              uint4v f;
              f.x = pack_bf16x2(xra[kt].x, xra[kt].y);
              f.y = pack_bf16x2(xra[kt].z, xra[kt].w);
              f.z = pack_bf16x2(xrb8[kt].x, xrb8[kt].y);
              f.w = pack_bf16x2(xrb8[kt].z, xrb8[kt].w);
              xsh[kt][lane] = f;
            }
          }
        }
        waitflag(&hsflag, (unsigned)(ri + 1));
        uint4v hf[8];
#pragma unroll
        for (int k = 0; k < 8; ++k) hf[k] = hsh[k][lane];
        float4v a1 = {0.f,0.f,0.f,0.f}, a2 = {0.f,0.f,0.f,0.f};
#pragma unroll
        for (int kt = 0; kt < 8; kt += 2) {
          MFMA1(a1, hf[kt],     Wf[2 + i][kt]);
          MFMA1(a2, hf[kt + 1], Wf[2 + i][kt + 1]);
        }
        float4v a = a1 + a2;
        if (v < 3) {                       // rr, zz get sigmoid; tn stays raw
#pragma unroll
          for (int j = 0; j < 4; ++j) a[j] = sigf(a[j]);
        }
        *(float4v*)&tiles[v - 1][lane * 4] = a;
        if (lane == 0) addrel(&tcnt);   // R6-bug fix: one add PER WAVE
      }
    }
  }
}

extern "C" void kernel_launch(void* const* d_in, const int* in_sizes, int n_in,
                              void* d_out, int out_size, void* d_ws, size_t ws_size,
                              hipStream_t stream) {
  (void)in_sizes; (void)n_in; (void)out_size; (void)ws_size;
  const float* x        = (const float*)d_in[0];
  const int* lengths    = (const int*)d_in[1];
  const float* Wr       = (const float*)d_in[2];
  const float* Wz       = (const float*)d_in[3];
  const float* Wl       = (const float*)d_in[4];
  const float* Wt       = (const float*)d_in[5];
  const float* Cx       = (const float*)d_in[6];
  const float* Ch       = (const float*)d_in[7];
  const float* Tr       = (const float*)d_in[8];
  const float* Tz       = (const float*)d_in[9];
  const float* Tn       = (const float*)d_in[10];

  unsigned char* hbuf = (unsigned char*)d_ws;

  // Ring init: all slots zero. tag 0 == "round -1 published"; slot 3 data
  // (zeros) is exactly h0. Must re-run every launch (ws is re-poisoned).
  hipMemsetAsync(hbuf, 0x00, HBUF_BYTES, stream);

  rnn_main<<<dim3(128), dim3(256), 0, stream>>>(
      x, lengths, Wr, Wz, Wl, Wt, Cx, Ch, Tr, Tz, Tn,
      hbuf, (float*)d_out);
}